// Round 8
// baseline (247.680 us; speedup 1.0000x reference)
//
#include <hip/hip_runtime.h>

#define B        4
#define N        16384       // 2^14
#define NPOINT   2048        // 2^11
#define C        64
#define NSAMPLE  32
#define CH       (C + 3)     // 67 output channels
#define RADIUS2  0.01f
#define NCELL    1000        // 10^3 cells per batch (cell size = radius)
#define CSTRIDE  1032        // cell_start row stride (ints) >= NCELL+1
#define CCSTRIDE 1024        // counter row stride (ints)
#define CAP      192         // per-query candidate cap (mean ~68, ~15 sigma)
#define K1GRID   1280        // 1024 transpose blocks + 256 count blocks

typedef float vfloat4 __attribute__((ext_vector_type(4)));  // for nontemporal

__device__ __forceinline__ int clamp10(int v) {
    return v < 0 ? 0 : (v > 9 ? 9 : v);
}

// ---------------------------------------------------------------------------
// k1: fused transpose + count + (last-block) prefix.
//   blocks 0..1023    : transpose tile (B,C,N)->(B,N,C), float4 both ways
//   blocks 1024..1279 : per-cell histogram via device-scope global atomics
//                       (cc pre-zeroed by hipMemsetAsync)
//   LAST block to finish (ticket on cc[1023], a spare zeroed slot): exclusive
//   scan of all B*1000 cells -> cs (cell starts) and cc (scatter cursors).
// grid = 1280, block = 256
// ---------------------------------------------------------------------------
__global__ __launch_bounds__(256) void prep_kernel(
    const float* __restrict__ xyz,   // (B,N,3)
    const float* __restrict__ f,     // (B,C,N)
    float* __restrict__ ft,          // (B,N,C)
    int* __restrict__ cc,            // (B, CCSTRIDE) counters (zeroed)
    int* __restrict__ cs)            // (B, CSTRIDE) cell starts
{
    const int t = threadIdx.x;
    __shared__ float tile[64][65];
    __shared__ int   wsum[256];
    __shared__ int   islast;

    if (blockIdx.x >= 1024) {
        // ---- count ----
        const int g = (blockIdx.x - 1024) * 256 + t;    // < B*N
        const int b = g >> 14;
        const float x = xyz[g * 3 + 0], y = xyz[g * 3 + 1], z = xyz[g * 3 + 2];
        const int cx = clamp10((int)(x * 10.f));
        const int cy = clamp10((int)(y * 10.f));
        const int cz = clamp10((int)(z * 10.f));
        atomicAdd(&cc[(b << 10) + (cx * 10 + cy) * 10 + cz], 1);
    } else {
        // ---- transpose tile ----
        const int tt = blockIdx.x;           // 0..1023
        const int b  = tt >> 8;              // 256 tiles per batch
        const int n0 = (tt & 255) * 64;
        const int r16 = t >> 4;              // 0..15
        const int x4  = t & 15;              // 0..15
        #pragma unroll
        for (int it = 0; it < 4; ++it) {
            const int cch = it * 16 + r16;
            const float4 v = *(const float4*)(f + ((size_t)b * C + cch) * N + n0 + x4 * 4);
            tile[cch][x4 * 4 + 0] = v.x;
            tile[cch][x4 * 4 + 1] = v.y;
            tile[cch][x4 * 4 + 2] = v.z;
            tile[cch][x4 * 4 + 3] = v.w;
        }
        __syncthreads();
        #pragma unroll
        for (int it = 0; it < 4; ++it) {
            const int nn = it * 16 + r16;
            float4 v;
            v.x = tile[x4 * 4 + 0][nn];
            v.y = tile[x4 * 4 + 1][nn];
            v.z = tile[x4 * 4 + 2][nn];
            v.w = tile[x4 * 4 + 3][nn];
            *(float4*)(ft + ((size_t)b * N + n0 + nn) * C + x4 * 4) = v;
        }
    }

    // ---- ticket: last finishing block runs the prefix scan ----
    __threadfence();                 // drain this thread's atomics/stores
    __syncthreads();
    if (t == 0) {
        const int done = atomicAdd(&cc[1023], 1);   // spare zeroed slot
        islast = (done == K1GRID - 1) ? 1 : 0;
    }
    __syncthreads();
    if (!islast) return;

    // exclusive scan per batch: 4 cells/thread + 256-wide Hillis-Steele
    for (int bb = 0; bb < B; ++bb) {
        int h[4];
        #pragma unroll
        for (int m = 0; m < 4; ++m) {
            const int cell = t * 4 + m;
            h[m] = (cell < NCELL)
                 ? __hip_atomic_load(&cc[(bb << 10) + cell],
                                     __ATOMIC_RELAXED, __HIP_MEMORY_SCOPE_AGENT)
                 : 0;
        }
        wsum[t] = h[0] + h[1] + h[2] + h[3];
        __syncthreads();
        for (int off = 1; off < 256; off <<= 1) {
            const int u = (t >= off) ? wsum[t - off] : 0;
            __syncthreads();
            wsum[t] += u;
            __syncthreads();
        }
        const int base = (t == 0) ? 0 : wsum[t - 1];
        const int c0 = base, c1 = c0 + h[0], c2 = c1 + h[1], c3 = c2 + h[2];
        int* csb = cs + bb * CSTRIDE;
        csb[t * 4 + 0] = c0;             // covers 0..1023 (>=1001 needed)
        csb[t * 4 + 1] = c1;
        csb[t * 4 + 2] = c2;
        csb[t * 4 + 3] = c3;
        cc[(bb << 10) + t * 4 + 0] = c0; // cursor init for scatter
        cc[(bb << 10) + t * 4 + 1] = c1;
        cc[(bb << 10) + t * 4 + 2] = c2;
        cc[(bb << 10) + t * 4 + 3] = c3;
        __syncthreads();
    }
}

// ---------------------------------------------------------------------------
// k2: scatter points to cell-sorted float4(x,y,z,bitcast(index)). 256 blocks.
// ---------------------------------------------------------------------------
__global__ __launch_bounds__(256) void scatter_kernel(const float* __restrict__ xyz,
                                                      int* __restrict__ cursor,
                                                      float4* __restrict__ sp) {
    const int g = blockIdx.x * 256 + threadIdx.x;
    const int b = g >> 14;
    const int n = g & (N - 1);
    const float x = xyz[g * 3 + 0], y = xyz[g * 3 + 1], z = xyz[g * 3 + 2];
    const int cx = clamp10((int)(x * 10.f));
    const int cy = clamp10((int)(y * 10.f));
    const int cz = clamp10((int)(z * 10.f));
    const int cell = (cx * 10 + cy) * 10 + cz;
    const int pos = atomicAdd(&cursor[(b << 10) + cell], 1);
    sp[(b << 14) + pos] = make_float4(x, y, z, __int_as_float(n));
}

// ---------------------------------------------------------------------------
// k3: fused ball query + grouping. One wave per query, 4 queries per block.
// LDS 3.6KB/block -> launch_bounds(256,8) -> 8 blocks/CU = 32 waves/CU.
//   Query: order-free flattened scan of the 9 z-runs (bounds in SGPRs via
//          readlane), ballot-append candidates, rank-select restores index
//          order. Wave-private LDS -> __threadfence_block() only.
//   Group: no LDS tile. Each lane gathers 4 slots of ONE channel (4 scattered
//          dword loads) and issues one float4 NT store -> 8 lanes with the
//          same ch form a 128B segment; 8.4 store instrs/query (vs 35 scalar).
// ---------------------------------------------------------------------------
__global__ __launch_bounds__(256, 8) void qg_kernel(
    const float*  __restrict__ xyz,      // (B,N,3)
    const float*  __restrict__ new_xyz,  // (B,NPOINT,3)
    const float*  __restrict__ ft,       // (B,N,C)
    const int*    __restrict__ cs,       // cell starts
    const float4* __restrict__ sp,       // cell-sorted points
    float* __restrict__ out_cnt,         // B*NPOINT
    float* __restrict__ out_feat)        // (B,CH,NPOINT,NSAMPLE)
{
    const int w = threadIdx.x >> 6;      // wave 0..3
    const int l = threadIdx.x & 63;
    const int q = blockIdx.x * 4 + w;    // 0..B*NPOINT-1
    const int b = q >> 11;
    const int j = q & (NPOINT - 1);

    __shared__ int cand_s[4][CAP];
    __shared__ int sidx_s[4][NSAMPLE];
    int* cand  = cand_s[w];
    int* s_idx = sidx_s[w];

    const float qx = new_xyz[q * 3 + 0];
    const float qy = new_xyz[q * 3 + 1];
    const float qz = new_xyz[q * 3 + 2];

    const int cx = clamp10((int)(qx * 10.f));
    const int cy = clamp10((int)(qy * 10.f));
    const int cz = clamp10((int)(qz * 10.f));
    const int z0 = cz > 0 ? cz - 1 : 0;
    const int z1 = cz < 9 ? cz + 1 : 9;

    // lanes 0..8 fetch the 9 run bounds (3x3 xy-cells, z contiguous)
    int sv = 0, ev = 0;
    if (l < 9) {
        const int xx = cx - 1 + l / 3;
        const int yy = cy - 1 + l % 3;
        if (xx >= 0 && xx <= 9 && yy >= 0 && yy <= 9) {
            const int cb = (xx * 10 + yy) * 10;
            sv = cs[b * CSTRIDE + cb + z0];
            ev = cs[b * CSTRIDE + cb + z1 + 1];
        }
    }
    const int len = ev - sv;

    // hoist run starts/lengths into uniform (SGPR) values
    int S[9], L[9];
    #pragma unroll
    for (int r = 0; r < 9; ++r) {
        S[r] = __builtin_amdgcn_readlane(sv, r);
        L[r] = __builtin_amdgcn_readlane(len, r);
    }
    int T = 0;
    #pragma unroll
    for (int r = 0; r < 9; ++r) T += L[r];

    const unsigned long long ltmask = (1ull << l) - 1ull;
    int total = 0, ncand = 0;
    for (int base = 0; base < T; base += 64) {
        const int wid = base + l;
        int p = 0, acc = 0;
        bool act = false;
        #pragma unroll
        for (int r = 0; r < 9; ++r) {
            const int off = wid - acc;
            if (off >= 0 && off < L[r]) { p = S[r] + off; act = true; }
            acc += L[r];
        }
        float4 pt = make_float4(1e9f, 1e9f, 1e9f, 0.f);
        if (act) pt = sp[(b << 14) + p];
        const float dx = pt.x - qx, dy = pt.y - qy, dz = pt.z - qz;
        const float d2 = dx * dx + dy * dy + dz * dz;
        const bool in = act && (d2 < RADIUS2);
        const unsigned long long m = __ballot(in);
        if (in) {
            const int slot = ncand + __popcll(m & ltmask);
            if (slot < CAP) cand[slot] = __float_as_int(pt.w);
        }
        const int c = __popcll(m);
        total += c;
        ncand = ncand + c > CAP ? CAP : ncand + c;
    }

    int cntv;
    if (total > CAP) {
        // overflow (astronomically unlikely for uniform data): ordered rescan
        const float* xb = xyz + (size_t)b * N * 3;
        int cnt2 = 0;
        for (int base = 0; base < N; base += 64) {
            const int p = base + l;
            const float dx = xb[p * 3 + 0] - qx;
            const float dy = xb[p * 3 + 1] - qy;
            const float dz = xb[p * 3 + 2] - qz;
            const float d2 = dx * dx + dy * dy + dz * dz;
            const bool in = d2 < RADIUS2;
            const unsigned long long m = __ballot(in);
            if (in) {
                const int slot = cnt2 + __popcll(m & ltmask);
                if (slot < NSAMPLE) s_idx[slot] = p;
            }
            cnt2 += __popcll(m);
            if (cnt2 >= NSAMPLE) break;
        }
        cntv = cnt2 < NSAMPLE ? cnt2 : NSAMPLE;
        __threadfence_block();
    } else {
        __threadfence_block();           // cand[] appends visible to wave
        const int K = ncand;             // == total
        for (int c = l; c < K; c += 64) {
            const int v = cand[c];
            int rnk = 0;
            for (int i = 0; i < K; ++i) rnk += (cand[i] < v) ? 1 : 0;
            if (rnk < NSAMPLE) s_idx[rnk] = v;   // first-32 in index order
        }
        cntv = total < NSAMPLE ? total : NSAMPLE;
        __threadfence_block();
    }

    // fill unfound slots with first index (0 if none)
    if (l < NSAMPLE && l >= cntv) s_idx[l] = (cntv > 0) ? s_idx[0] : 0;
    __threadfence_block();

    if (l == 0) out_cnt[q] = (float)cntv;

    // ---- gather + float4 NT store (no LDS tile, no barrier) ----
    // lane covers (ch = e4>>3, 4 slots k = 4*(e4&7)..+3); 8 lanes same ch
    // -> one 128B segment; one store instr covers 8 such segments.
    for (int e4 = l; e4 < CH * 8; e4 += 64) {
        const int ch = e4 >> 3;
        const int k4 = (e4 & 7) * 4;
        const int i0 = s_idx[k4 + 0];
        const int i1 = s_idx[k4 + 1];
        const int i2 = s_idx[k4 + 2];
        const int i3 = s_idx[k4 + 3];
        vfloat4 v;
        if (ch < 3) {
            const float qc = (ch == 0) ? qx : ((ch == 1) ? qy : qz);
            v.x = xyz[((size_t)b * N + i0) * 3 + ch] - qc;
            v.y = xyz[((size_t)b * N + i1) * 3 + ch] - qc;
            v.z = xyz[((size_t)b * N + i2) * 3 + ch] - qc;
            v.w = xyz[((size_t)b * N + i3) * 3 + ch] - qc;
        } else {
            const int c = ch - 3;
            v.x = ft[((size_t)b * N + i0) * C + c];
            v.y = ft[((size_t)b * N + i1) * C + c];
            v.z = ft[((size_t)b * N + i2) * C + c];
            v.w = ft[((size_t)b * N + i3) * C + c];
        }
        vfloat4* op = (vfloat4*)(out_feat +
                      ((size_t)(b * CH + ch) * NPOINT + j) * NSAMPLE) + (e4 & 7);
        __builtin_nontemporal_store(v, op);
    }
}

// ---------------------------------------------------------------------------
// Fallback (small workspace): linear-scan fused kernel, no grid, no transpose.
// ---------------------------------------------------------------------------
__global__ __launch_bounds__(64) void qg_wave_kernel(
    const float* __restrict__ xyz,
    const float* __restrict__ new_xyz,
    const float* __restrict__ feat,      // (B,C,N) original layout
    float* __restrict__ out_cnt,
    float* __restrict__ out_feat)
{
    const int q = blockIdx.x;
    const int b = q >> 11;
    const int j = q & (NPOINT - 1);
    const int l = threadIdx.x;

    __shared__ int s_idx[NSAMPLE];

    const float qx = new_xyz[q * 3 + 0];
    const float qy = new_xyz[q * 3 + 1];
    const float qz = new_xyz[q * 3 + 2];
    const float* xb = xyz + (size_t)b * N * 3;

    int cnt = 0;
    for (int base = 0; base < N; base += 64) {
        const int p = base + l;
        const float dx = xb[p * 3 + 0] - qx;
        const float dy = xb[p * 3 + 1] - qy;
        const float dz = xb[p * 3 + 2] - qz;
        const float d2 = dx * dx + dy * dy + dz * dz;
        const bool in = d2 < RADIUS2;
        const unsigned long long m = __ballot(in);
        if (in) {
            const int slot = cnt + __popcll(m & ((1ull << l) - 1ull));
            if (slot < NSAMPLE) s_idx[slot] = p;
        }
        cnt += __popcll(m);
        if (cnt >= NSAMPLE) break;
    }
    if (cnt > NSAMPLE) cnt = NSAMPLE;

    if (l == 0) out_cnt[q] = (float)cnt;
    __syncthreads();
    if (l < NSAMPLE && l >= cnt) s_idx[l] = (cnt > 0) ? s_idx[0] : 0;
    __syncthreads();

    for (int e4 = l; e4 < CH * 8; e4 += 64) {
        const int ch = e4 >> 3;
        const int k4 = (e4 & 7) * 4;
        const int i0 = s_idx[k4 + 0];
        const int i1 = s_idx[k4 + 1];
        const int i2 = s_idx[k4 + 2];
        const int i3 = s_idx[k4 + 3];
        float4 v;
        if (ch < 3) {
            const float qc = (ch == 0) ? qx : ((ch == 1) ? qy : qz);
            v.x = xyz[((size_t)b * N + i0) * 3 + ch] - qc;
            v.y = xyz[((size_t)b * N + i1) * 3 + ch] - qc;
            v.z = xyz[((size_t)b * N + i2) * 3 + ch] - qc;
            v.w = xyz[((size_t)b * N + i3) * 3 + ch] - qc;
        } else {
            const int c = ch - 3;
            v.x = feat[((size_t)b * C + c) * N + i0];
            v.y = feat[((size_t)b * C + c) * N + i1];
            v.z = feat[((size_t)b * C + c) * N + i2];
            v.w = feat[((size_t)b * C + c) * N + i3];
        }
        float4* op = (float4*)(out_feat +
                     ((size_t)(b * CH + ch) * NPOINT + j) * NSAMPLE) + (e4 & 7);
        *op = v;
    }
}

extern "C" void kernel_launch(void* const* d_in, const int* in_sizes, int n_in,
                              void* d_out, int out_size, void* d_ws, size_t ws_size,
                              hipStream_t stream) {
    const float* xyz      = (const float*)d_in[0];   // (B,N,3)
    const float* new_xyz  = (const float*)d_in[1];   // (B,NPOINT,3)
    const float* features = (const float*)d_in[2];   // (B,C,N)

    float* out_cnt  = (float*)d_out;                 // B*NPOINT
    float* out_feat = out_cnt + (size_t)B * NPOINT;  // (B,CH,NPOINT,NSAMPLE)

    char* ws = (char*)d_ws;
    const size_t ftB = (size_t)B * N * C * sizeof(float);     // 16 MB
    const size_t spB = (size_t)B * N * sizeof(float4);        // 4 MB
    const size_t csB = (size_t)B * CSTRIDE * sizeof(int);
    const size_t ccB = (size_t)B * CCSTRIDE * sizeof(int);
    const size_t need = ftB + spB + csB + ccB;

    if (ws_size >= need) {
        float*  ft = (float*)ws;
        float4* sp = (float4*)(ws + ftB);
        int*    cs = (int*)(ws + ftB + spB);
        int*    cc = (int*)(ws + ftB + spB + csB);
        hipMemsetAsync(cc, 0, ccB, stream);   // legal graph memset node
        prep_kernel<<<K1GRID, 256, 0, stream>>>(xyz, features, ft, cc, cs);
        scatter_kernel<<<B * N / 256, 256, 0, stream>>>(xyz, cc, sp);
        qg_kernel<<<B * NPOINT / 4, 256, 0, stream>>>(xyz, new_xyz, ft, cs, sp,
                                                      out_cnt, out_feat);
    } else {
        qg_wave_kernel<<<B * NPOINT, 64, 0, stream>>>(xyz, new_xyz, features,
                                                      out_cnt, out_feat);
    }
}